// Round 3
// baseline (4823.332 us; speedup 1.0000x reference)
//
#include <hip/hip_runtime.h>
#include <math.h>

#define B_SZ 32
#define T_LEN 2048
#define I_DIM 128
#define H_DIM 256
#define ROWS 32   // rows per workgroup in the two GEMM kernels

// 64-way literal repetition (token-pasting needs literal tokens, no arithmetic)
#define REP64(M) M(0)M(1)M(2)M(3)M(4)M(5)M(6)M(7)M(8)M(9)M(10)M(11)M(12)M(13)M(14)M(15) \
                 M(16)M(17)M(18)M(19)M(20)M(21)M(22)M(23)M(24)M(25)M(26)M(27)M(28)M(29)M(30)M(31) \
                 M(32)M(33)M(34)M(35)M(36)M(37)M(38)M(39)M(40)M(41)M(42)M(43)M(44)M(45)M(46)M(47) \
                 M(48)M(49)M(50)M(51)M(52)M(53)M(54)M(55)M(56)M(57)M(58)M(59)M(60)M(61)M(62)M(63)

__device__ __forceinline__ float fast_tanh(float y) {
    // tanh(y) = 1 - 2/(e^{2y}+1); saturates correctly for |y| large (inf -> 1)
    float e = __expf(2.f * y);
    return 1.f - 2.f / (e + 1.f);
}

// ---------------------------------------------------------------------------
// Phase 1: xB[r][j] = sum_k x[r][k] * Bm[k][j]   (k < 128)
// No LDS: x row-chunks are wave-uniform -> scalar (s_load) broadcasts feeding
// v_fma's SGPR operand; Bm column j stays per-lane (coalesced vector loads).
// ---------------------------------------------------------------------------
__global__ __launch_bounds__(256) void xb_proj(const float* __restrict__ x,
                                               const float* __restrict__ Bm,
                                               float* __restrict__ xB) {
    const int j = threadIdx.x;
    const long r0 = (long)blockIdx.x * ROWS;

    float acc[ROWS];
#pragma unroll
    for (int r = 0; r < ROWS; ++r) acc[r] = 0.f;

#pragma unroll 4
    for (int k4 = 0; k4 < I_DIM / 4; ++k4) {
        const float wx = Bm[(4 * k4 + 0) * H_DIM + j];
        const float wy = Bm[(4 * k4 + 1) * H_DIM + j];
        const float wz = Bm[(4 * k4 + 2) * H_DIM + j];
        const float ww = Bm[(4 * k4 + 3) * H_DIM + j];
#pragma unroll
        for (int r = 0; r < ROWS; ++r) {
            float4 xv = *(const float4*)(x + (r0 + r) * I_DIM + 4 * k4);  // uniform
            acc[r] = fmaf(xv.x, wx, acc[r]);
            acc[r] = fmaf(xv.y, wy, acc[r]);
            acc[r] = fmaf(xv.z, wz, acc[r]);
            acc[r] = fmaf(xv.w, ww, acc[r]);
        }
    }
#pragma unroll
    for (int r = 0; r < ROWS; ++r)
        xB[(r0 + r) * H_DIM + j] = acc[r];
}

// ---------------------------------------------------------------------------
// Phase 2: recurrence. One WG = 256 threads (4 waves) per chain; thread j owns
// output column j completely: A[:,j] in 64 NAMED float4s (no array -> no
// scratch demotion). h round-trips through global hs (needed as output
// anyway); next step re-reads it via wave-uniform s_load_dwordx4 broadcasts.
// Zero LDS, zero shuffles, zero cross-lane reduction.
// ---------------------------------------------------------------------------
__global__ __launch_bounds__(256, 1) void rnn_scan(const float* __restrict__ A,
                                                   const float* __restrict__ xB,
                                                   float* __restrict__ hs) {
    const int j = threadIdx.x;
    const int b = blockIdx.x;

#define ADECL(K) float4 a##K;
    REP64(ADECL)
#undef ADECL
#define ALOAD(K) a##K = make_float4(A[(4 * K + 0) * H_DIM + j], \
                                    A[(4 * K + 1) * H_DIM + j], \
                                    A[(4 * K + 2) * H_DIM + j], \
                                    A[(4 * K + 3) * H_DIM + j]);
    REP64(ALOAD)
#undef ALOAD

    const long base = (long)b * T_LEN * H_DIM;
    const float* __restrict__ xbp = xB + base + j;
    float* __restrict__ hp = hs + base + j;

    // t = 0: h_prev = 0 -> h = tanh(xb)
    float xbn = xbp[0];
    float hn = fast_tanh(xbn);
    hp[0] = hn;
    xbn = xbp[H_DIM];   // prefetch t=1
    __syncthreads();

    for (int t = 1; t < T_LEN; ++t) {
        const float4* __restrict__ h4 =
            (const float4*)(hs + base + (long)(t - 1) * H_DIM);  // uniform base
        float y0 = 0.f, y1 = 0.f, y2 = 0.f, y3 = 0.f;
#define FMA4(K) { float4 hv = h4[K]; \
        y0 = fmaf(hv.x, a##K.x, y0); \
        y1 = fmaf(hv.y, a##K.y, y1); \
        y2 = fmaf(hv.z, a##K.z, y2); \
        y3 = fmaf(hv.w, a##K.w, y3); }
        REP64(FMA4)
#undef FMA4
        float y = (y0 + y1) + (y2 + y3) + xbn;
        hn = fast_tanh(y);
        hp[(long)t * H_DIM] = hn;
        if (t + 1 < T_LEN) xbn = xbp[(long)(t + 1) * H_DIM];  // prefetch
        __syncthreads();   // drains vmcnt: step-t stores visible before t+1 loads
    }
}

// ---------------------------------------------------------------------------
// Phase 3: out[r][j] = sum_k hs[r][k] * C[k][j] — in place on d_out.
// No LDS: hs row values are wave-uniform scalar broadcasts; all loads precede
// all stores within the WG's 32 private rows, so in-place is safe.
// ---------------------------------------------------------------------------
__global__ __launch_bounds__(256) void out_proj(float* __restrict__ hs_out,
                                                const float* __restrict__ C) {
    const int j = threadIdx.x;
    const long r0 = (long)blockIdx.x * ROWS;

    float acc[ROWS];
#pragma unroll
    for (int r = 0; r < ROWS; ++r) acc[r] = 0.f;

#pragma unroll 4
    for (int k4 = 0; k4 < H_DIM / 4; ++k4) {
        const float wx = C[(4 * k4 + 0) * H_DIM + j];
        const float wy = C[(4 * k4 + 1) * H_DIM + j];
        const float wz = C[(4 * k4 + 2) * H_DIM + j];
        const float ww = C[(4 * k4 + 3) * H_DIM + j];
#pragma unroll
        for (int r = 0; r < ROWS; ++r) {
            float4 hv = *(const float4*)(hs_out + (r0 + r) * H_DIM + 4 * k4);  // uniform
            acc[r] = fmaf(hv.x, wx, acc[r]);
            acc[r] = fmaf(hv.y, wy, acc[r]);
            acc[r] = fmaf(hv.z, wz, acc[r]);
            acc[r] = fmaf(hv.w, ww, acc[r]);
        }
    }
#pragma unroll
    for (int r = 0; r < ROWS; ++r)
        hs_out[(r0 + r) * H_DIM + j] = acc[r];
}

// ---------------------------------------------------------------------------
extern "C" void kernel_launch(void* const* d_in, const int* in_sizes, int n_in,
                              void* d_out, int out_size, void* d_ws, size_t ws_size,
                              hipStream_t stream) {
    const float* x  = (const float*)d_in[0];
    const float* A  = (const float*)d_in[1];
    const float* Bm = (const float*)d_in[2];
    const float* C  = (const float*)d_in[3];
    float* out = (float*)d_out;
    float* xB  = (float*)d_ws;   // 64 MB scratch

    const int R = B_SZ * T_LEN;  // 65536 rows

    xb_proj<<<R / ROWS, 256, 0, stream>>>(x, Bm, xB);
    rnn_scan<<<B_SZ, 256, 0, stream>>>(A, xB, out);
    out_proj<<<R / ROWS, 256, 0, stream>>>(out, C);
}

// Round 5
// 4576.520 us; speedup vs baseline: 1.0539x; 1.0539x over previous
//
#include <hip/hip_runtime.h>
#include <math.h>

#define B_SZ 32
#define T_LEN 2048
#define I_DIM 128
#define H_DIM 256
#define ROWS 32   // rows per workgroup in the two GEMM kernels

// 64-way literal repetition
#define REP64(M) M(0)M(1)M(2)M(3)M(4)M(5)M(6)M(7)M(8)M(9)M(10)M(11)M(12)M(13)M(14)M(15) \
                 M(16)M(17)M(18)M(19)M(20)M(21)M(22)M(23)M(24)M(25)M(26)M(27)M(28)M(29)M(30)M(31) \
                 M(32)M(33)M(34)M(35)M(36)M(37)M(38)M(39)M(40)M(41)M(42)M(43)M(44)M(45)M(46)M(47) \
                 M(48)M(49)M(50)M(51)M(52)M(53)M(54)M(55)M(56)M(57)M(58)M(59)M(60)M(61)M(62)M(63)

__device__ __forceinline__ float fast_tanh(float y) {
    // tanh(y) = 1 - 2/(e^{2y}+1); saturates correctly for |y| large
    float e = __expf(2.f * y);
    return 1.f - 2.f / (e + 1.f);
}

// ---------------------------------------------------------------------------
// Phase 1: xB[r][j] = sum_k x[r][k] * Bm[k][j]  (R2 version: LDS-staged x)
// ---------------------------------------------------------------------------
__global__ __launch_bounds__(256) void xb_proj(const float* __restrict__ x,
                                               const float* __restrict__ Bm,
                                               float* __restrict__ xB) {
    __shared__ float4 xt[ROWS][I_DIM / 4 + 1];
    const int tid = threadIdx.x;
    const int j = tid;
    const long r0 = (long)blockIdx.x * ROWS;

    const float4* xg = (const float4*)(x + r0 * I_DIM);
#pragma unroll
    for (int i = 0; i < 4; ++i) {
        int f = tid + i * 256;
        int rr = f >> 5;
        int kg = f & 31;
        xt[rr][kg] = xg[rr * 32 + kg];
    }
    __syncthreads();

    float acc[ROWS];
#pragma unroll
    for (int r = 0; r < ROWS; ++r) acc[r] = 0.f;

    for (int k = 0; k < I_DIM; k += 4) {
        float w0 = Bm[(k + 0) * H_DIM + j];
        float w1 = Bm[(k + 1) * H_DIM + j];
        float w2 = Bm[(k + 2) * H_DIM + j];
        float w3 = Bm[(k + 3) * H_DIM + j];
#pragma unroll
        for (int r = 0; r < ROWS; ++r) {
            float4 hv = xt[r][k >> 2];
            acc[r] = fmaf(hv.x, w0, acc[r]);
            acc[r] = fmaf(hv.y, w1, acc[r]);
            acc[r] = fmaf(hv.z, w2, acc[r]);
            acc[r] = fmaf(hv.w, w3, acc[r]);
        }
    }
#pragma unroll
    for (int r = 0; r < ROWS; ++r)
        xB[(r0 + r) * H_DIM + j] = acc[r];
}

// ---------------------------------------------------------------------------
// Phase 2: recurrence. 256 threads (4 waves) per chain; thread j owns column j:
// A[:,j] in 64 named float4s, PINNED in VGPRs by asm-opacity (values become
// asm outputs -> the compiler cannot rematerialize them by reloading A, which
// is what round 3's VGPR=164 showed it was doing). Budget: launch_bounds
// (256,1) -> 512 VGPR/lane; need ~290.
// h round-trips through global hs (L2-resident, written-once-read-once).
// ---------------------------------------------------------------------------
__global__ __launch_bounds__(256, 1) void rnn_scan(const float* __restrict__ A,
                                                   const float* __restrict__ xB,
                                                   float* __restrict__ hs) {
    const int j = threadIdx.x;
    const int b = blockIdx.x;

#define ADECL(K) float4 a##K;
    REP64(ADECL)
#undef ADECL
#define ALOAD(K) a##K = make_float4(A[(4 * K + 0) * H_DIM + j], \
                                    A[(4 * K + 1) * H_DIM + j], \
                                    A[(4 * K + 2) * H_DIM + j], \
                                    A[(4 * K + 3) * H_DIM + j]);
    REP64(ALOAD)
#undef ALOAD
    // Pin: make every A value an asm output so it cannot be re-loaded from
    // memory inside the loop; allocator must keep them live in VGPRs.
#define APIN(K) asm volatile("" : "+v"(a##K.x), "+v"(a##K.y), "+v"(a##K.z), "+v"(a##K.w));
    REP64(APIN)
#undef APIN

    const long base = (long)b * T_LEN * H_DIM;
    const float* __restrict__ xbp = xB + base + j;
    float* __restrict__ hp = hs + base + j;

    // t = 0: h_prev = 0 -> h = tanh(xb)
    float xbn = xbp[0];
    float hn = fast_tanh(xbn);
    hp[0] = hn;
    xbn = xbp[H_DIM];   // prefetch t=1
    __syncthreads();

    for (int t = 1; t < T_LEN; ++t) {
        const float4* __restrict__ h4 =
            (const float4*)(hs + base + (long)(t - 1) * H_DIM);  // uniform base
        float y0 = 0.f, y1 = 0.f, y2 = 0.f, y3 = 0.f;
#define FMA4(K) { float4 hv = h4[K]; \
        y0 = fmaf(hv.x, a##K.x, y0); \
        y1 = fmaf(hv.y, a##K.y, y1); \
        y2 = fmaf(hv.z, a##K.z, y2); \
        y3 = fmaf(hv.w, a##K.w, y3); }
        REP64(FMA4)
#undef FMA4
        float y = (y0 + y1) + (y2 + y3) + xbn;
        hn = fast_tanh(y);
        hp[(long)t * H_DIM] = hn;
        if (t + 1 < T_LEN) xbn = xbp[(long)(t + 1) * H_DIM];  // prefetch
        __syncthreads();   // step-t stores drained & visible before t+1 loads
    }
}

// ---------------------------------------------------------------------------
// Phase 3: out[r][j] = sum_k hs[r][k] * C[k][j]  (R2 version, in place)
// ---------------------------------------------------------------------------
__global__ __launch_bounds__(256) void out_proj(float* __restrict__ hs_out,
                                                const float* __restrict__ C) {
    __shared__ float4 ht[ROWS][H_DIM / 4 + 1];
    const int tid = threadIdx.x;
    const int j = tid;
    const long r0 = (long)blockIdx.x * ROWS;

    const float4* hg = (const float4*)(hs_out + r0 * H_DIM);
#pragma unroll
    for (int i = 0; i < 8; ++i) {
        int f = tid + i * 256;
        int rr = f >> 6;
        int kg = f & 63;
        ht[rr][kg] = hg[rr * 64 + kg];
    }
    __syncthreads();

    float acc[ROWS];
#pragma unroll
    for (int r = 0; r < ROWS; ++r) acc[r] = 0.f;

    for (int k = 0; k < H_DIM; k += 4) {
        float w0 = C[(k + 0) * H_DIM + j];
        float w1 = C[(k + 1) * H_DIM + j];
        float w2 = C[(k + 2) * H_DIM + j];
        float w3 = C[(k + 3) * H_DIM + j];
#pragma unroll
        for (int r = 0; r < ROWS; ++r) {
            float4 hv = ht[r][k >> 2];
            acc[r] = fmaf(hv.x, w0, acc[r]);
            acc[r] = fmaf(hv.y, w1, acc[r]);
            acc[r] = fmaf(hv.z, w2, acc[r]);
            acc[r] = fmaf(hv.w, w3, acc[r]);
        }
    }
#pragma unroll
    for (int r = 0; r < ROWS; ++r)
        hs_out[(r0 + r) * H_DIM + j] = acc[r];
}

// ---------------------------------------------------------------------------
extern "C" void kernel_launch(void* const* d_in, const int* in_sizes, int n_in,
                              void* d_out, int out_size, void* d_ws, size_t ws_size,
                              hipStream_t stream) {
    const float* x  = (const float*)d_in[0];
    const float* A  = (const float*)d_in[1];
    const float* Bm = (const float*)d_in[2];
    const float* C  = (const float*)d_in[3];
    float* out = (float*)d_out;
    float* xB  = (float*)d_ws;   // 64 MB scratch

    const int R = B_SZ * T_LEN;  // 65536 rows

    xb_proj<<<R / ROWS, 256, 0, stream>>>(x, Bm, xB);
    rnn_scan<<<B_SZ, 256, 0, stream>>>(A, xB, out);
    out_proj<<<R / ROWS, 256, 0, stream>>>(out, C);
}

// Round 6
// 2499.484 us; speedup vs baseline: 1.9297x; 1.8310x over previous
//
#include <hip/hip_runtime.h>
#include <math.h>

#define B_SZ 32
#define T_LEN 2048
#define I_DIM 128
#define H_DIM 256
#define ROWS 32   // rows per workgroup in the two GEMM kernels

// 32-way literal repetition
#define REP32(M) M(0)M(1)M(2)M(3)M(4)M(5)M(6)M(7)M(8)M(9)M(10)M(11)M(12)M(13)M(14)M(15) \
                 M(16)M(17)M(18)M(19)M(20)M(21)M(22)M(23)M(24)M(25)M(26)M(27)M(28)M(29)M(30)M(31)

__device__ __forceinline__ float fast_tanh(float y) {
    // tanh(y) = 1 - 2/(e^{2y}+1); saturates correctly for |y| large
    float e = __expf(2.f * y);
    return 1.f - 2.f / (e + 1.f);
}

// ---------------------------------------------------------------------------
// Phase 1: xB[r][j] = sum_k x[r][k] * Bm[k][j]  (R2 version: LDS-staged x)
// ---------------------------------------------------------------------------
__global__ __launch_bounds__(256) void xb_proj(const float* __restrict__ x,
                                               const float* __restrict__ Bm,
                                               float* __restrict__ xB) {
    __shared__ float4 xt[ROWS][I_DIM / 4 + 1];
    const int tid = threadIdx.x;
    const int j = tid;
    const long r0 = (long)blockIdx.x * ROWS;

    const float4* xg = (const float4*)(x + r0 * I_DIM);
#pragma unroll
    for (int i = 0; i < 4; ++i) {
        int f = tid + i * 256;
        int rr = f >> 5;
        int kg = f & 31;
        xt[rr][kg] = xg[rr * 32 + kg];
    }
    __syncthreads();

    float acc[ROWS];
#pragma unroll
    for (int r = 0; r < ROWS; ++r) acc[r] = 0.f;

    for (int k = 0; k < I_DIM; k += 4) {
        float w0 = Bm[(k + 0) * H_DIM + j];
        float w1 = Bm[(k + 1) * H_DIM + j];
        float w2 = Bm[(k + 2) * H_DIM + j];
        float w3 = Bm[(k + 3) * H_DIM + j];
#pragma unroll
        for (int r = 0; r < ROWS; ++r) {
            float4 hv = xt[r][k >> 2];
            acc[r] = fmaf(hv.x, w0, acc[r]);
            acc[r] = fmaf(hv.y, w1, acc[r]);
            acc[r] = fmaf(hv.z, w2, acc[r]);
            acc[r] = fmaf(hv.w, w3, acc[r]);
        }
    }
#pragma unroll
    for (int r = 0; r < ROWS; ++r)
        xB[(r0 + r) * H_DIM + j] = acc[r];
}

// ---------------------------------------------------------------------------
// Phase 2: recurrence. 512 threads (8 waves) per chain. Lane pair (2j, 2j+1)
// owns column j: thread (col=tid>>1, kh=tid&1) holds the kh-half of A[:,col]
// in 32 NAMED+PINNED float4s = 128 floats (~170 VGPR demand, safely under the
// 256 arch-VGPR wall that doomed R3/R5's 286-demand layout).
// h double-buffered in LDS (2x1KB): even/odd lanes read their half as
// ds_read_b128 -> 2 addresses/wave, broadcast to 32 lanes each (2-way
// multicast = free). Pair-reduce via one __shfl_xor. ONE barrier per step.
// ---------------------------------------------------------------------------
__global__ __launch_bounds__(512, 2) void rnn_scan(const float* __restrict__ A,
                                                   const float* __restrict__ xB,
                                                   float* __restrict__ hs) {
    __shared__ __align__(16) float hbuf[2][H_DIM];
    const int tid = threadIdx.x;
    const int col = tid >> 1;    // 0..255: output column
    const int kh  = tid & 1;     // which K-half this thread sums
    const int b = blockIdx.x;

#define ADECL(K) float4 a##K;
    REP32(ADECL)
#undef ADECL
#define ALOAD(K) a##K = make_float4(A[(kh * 128 + 4 * K + 0) * H_DIM + col], \
                                    A[(kh * 128 + 4 * K + 1) * H_DIM + col], \
                                    A[(kh * 128 + 4 * K + 2) * H_DIM + col], \
                                    A[(kh * 128 + 4 * K + 3) * H_DIM + col]);
    REP32(ALOAD)
#undef ALOAD
    // Pin: values become asm outputs -> not rematerializable; demand fits the
    // register file this time, so no spill either.
#define APIN(K) asm volatile("" : "+v"(a##K.x), "+v"(a##K.y), "+v"(a##K.z), "+v"(a##K.w));
    REP32(APIN)
#undef APIN

    const long base = (long)b * T_LEN * H_DIM;
    const float* __restrict__ xbp = xB + base + col;
    float* __restrict__ hp = hs + base + col;

    // t = 0: h_prev = 0 -> h = tanh(xb)
    float xbn = xbp[0];
    float hn = fast_tanh(xbn);
    if (kh == 0) { hbuf[0][col] = hn; hp[0] = hn; }
    xbn = xbp[H_DIM];   // prefetch t=1
    __syncthreads();

    for (int t = 1; t < T_LEN; ++t) {
        const float4* __restrict__ h4 = (const float4*)(&hbuf[(t + 1) & 1][kh * 128]);
        // issue next-step xb prefetch before the FMA chain (hide L2 latency)
        const int tn = (t + 1 < T_LEN) ? t + 1 : t;
        float xbn2 = xbp[(long)tn * H_DIM];

        float y0 = 0.f, y1 = 0.f, y2 = 0.f, y3 = 0.f;
#define FMA4(K) { float4 hv = h4[K]; \
        y0 = fmaf(hv.x, a##K.x, y0); \
        y1 = fmaf(hv.y, a##K.y, y1); \
        y2 = fmaf(hv.z, a##K.z, y2); \
        y3 = fmaf(hv.w, a##K.w, y3); }
        REP32(FMA4)
#undef FMA4
        float y = (y0 + y1) + (y2 + y3);
        y += __shfl_xor(y, 1);          // combine the two K-halves (lane pair)
        y += xbn;
        hn = fast_tanh(y);
        if (kh == 0) {
            hbuf[t & 1][col] = hn;      // 32 distinct banks across the wave
            hp[(long)t * H_DIM] = hn;   // contiguous 128B per wave
        }
        xbn = xbn2;
        __syncthreads();                // h_t visible to all waves for t+1
    }
}

// ---------------------------------------------------------------------------
// Phase 3: out[r][j] = sum_k hs[r][k] * C[k][j]  (R2 version, in place)
// ---------------------------------------------------------------------------
__global__ __launch_bounds__(256) void out_proj(float* __restrict__ hs_out,
                                                const float* __restrict__ C) {
    __shared__ float4 ht[ROWS][H_DIM / 4 + 1];
    const int tid = threadIdx.x;
    const int j = tid;
    const long r0 = (long)blockIdx.x * ROWS;

    const float4* hg = (const float4*)(hs_out + r0 * H_DIM);
#pragma unroll
    for (int i = 0; i < 8; ++i) {
        int f = tid + i * 256;
        int rr = f >> 6;
        int kg = f & 63;
        ht[rr][kg] = hg[rr * 64 + kg];
    }
    __syncthreads();

    float acc[ROWS];
#pragma unroll
    for (int r = 0; r < ROWS; ++r) acc[r] = 0.f;

    for (int k = 0; k < H_DIM; k += 4) {
        float w0 = C[(k + 0) * H_DIM + j];
        float w1 = C[(k + 1) * H_DIM + j];
        float w2 = C[(k + 2) * H_DIM + j];
        float w3 = C[(k + 3) * H_DIM + j];
#pragma unroll
        for (int r = 0; r < ROWS; ++r) {
            float4 hv = ht[r][k >> 2];
            acc[r] = fmaf(hv.x, w0, acc[r]);
            acc[r] = fmaf(hv.y, w1, acc[r]);
            acc[r] = fmaf(hv.z, w2, acc[r]);
            acc[r] = fmaf(hv.w, w3, acc[r]);
        }
    }
#pragma unroll
    for (int r = 0; r < ROWS; ++r)
        hs_out[(r0 + r) * H_DIM + j] = acc[r];
}

// ---------------------------------------------------------------------------
extern "C" void kernel_launch(void* const* d_in, const int* in_sizes, int n_in,
                              void* d_out, int out_size, void* d_ws, size_t ws_size,
                              hipStream_t stream) {
    const float* x  = (const float*)d_in[0];
    const float* A  = (const float*)d_in[1];
    const float* Bm = (const float*)d_in[2];
    const float* C  = (const float*)d_in[3];
    float* out = (float*)d_out;
    float* xB  = (float*)d_ws;   // 64 MB scratch

    const int R = B_SZ * T_LEN;  // 65536 rows

    xb_proj<<<R / ROWS, 256, 0, stream>>>(x, Bm, xB);
    rnn_scan<<<B_SZ, 512, 0, stream>>>(A, xB, out);
    out_proj<<<R / ROWS, 256, 0, stream>>>(out, C);
}